// Round 1
// 214.292 us; speedup vs baseline: 1.0753x; 1.0753x over previous
//
#include <hip/hip_runtime.h>
#include <hip/hip_fp16.h>

#define DFEAT 64
#define NG 64
#define TILE 128        // nodes per bucket/tile (bucket = tgt >> 7)
#define NBLK 256        // binning blocks
#define NBMAX 1024      // max buckets supported in LDS

// ---------------- pass A: per-block-chunk bucket histogram -> cnt_m[blk][b] -----
__global__ __launch_bounds__(256) void k_cnt(const int* __restrict__ col,
                                             int* __restrict__ cnt_m,
                                             int e, int nb, int chunk) {
  __shared__ int hist[NBMAX];
  int tid = threadIdx.x;
  int blk = blockIdx.x;
  for (int b = tid; b < nb; b += 256) hist[b] = 0;
  __syncthreads();
  int lo = blk * chunk, hi = min(lo + chunk, e);
  for (int i = lo + tid; i < hi; i += 256)
    atomicAdd(&hist[col[i] >> 7], 1);
  __syncthreads();
  for (int b = tid; b < nb; b += 256)
    cnt_m[(size_t)blk * nb + b] = hist[b];
}

// ---------------- pass B: per-bucket scan over blocks (in place) + totals -------
__global__ __launch_bounds__(256) void k_colscan(int* __restrict__ cnt_m,
                                                 int* __restrict__ gcount, int nb) {
  __shared__ int sh[256];
  int tid = threadIdx.x;
  int b = blockIdx.x;
  int v = cnt_m[(size_t)tid * nb + b];
  sh[tid] = v;
  __syncthreads();
  for (int off = 1; off < 256; off <<= 1) {
    int t = (tid >= off) ? sh[tid - off] : 0;
    __syncthreads();
    sh[tid] += t;
    __syncthreads();
  }
  cnt_m[(size_t)tid * nb + b] = sh[tid] - v;  // exclusive over blocks
  if (tid == 255) gcount[b] = sh[255];
}

// ---------------- scan bucket totals -> base[0..nb] ----------------------------
__global__ __launch_bounds__(1024) void k_bscan(const int* __restrict__ gcount,
                                                int* __restrict__ base, int nb) {
  __shared__ int sh[1024];
  int tid = threadIdx.x;
  int v = (tid < nb) ? gcount[tid] : 0;
  sh[tid] = v;
  __syncthreads();
  for (int off = 1; off < 1024; off <<= 1) {
    int t = (tid >= off) ? sh[tid - off] : 0;
    __syncthreads();
    sh[tid] += t;
    __syncthreads();
  }
  if (tid < nb) base[tid] = sh[tid] - v;
  if (tid == 0) base[nb] = sh[1023];
}

// ---------------- pass C: place edges, LDS cursors only, packed payload --------
// pairs[pos] = src | ((tgt & 127) << 20)   (requires n < 2^20)
__global__ __launch_bounds__(256) void k_bin2(const int* __restrict__ row,
                                              const int* __restrict__ col,
                                              const int* __restrict__ base,
                                              const int* __restrict__ cnt_m,
                                              int* __restrict__ pairs,
                                              int e, int nb, int chunk) {
  __shared__ int gl[NBMAX];
  __shared__ int lcur[NBMAX];
  int tid = threadIdx.x;
  int blk = blockIdx.x;
  for (int b = tid; b < nb; b += 256) {
    gl[b] = base[b] + cnt_m[(size_t)blk * nb + b];
    lcur[b] = 0;
  }
  __syncthreads();
  int lo = blk * chunk, hi = min(lo + chunk, e);
  for (int i = lo + tid; i < hi; i += 256) {
    int s = row[i], t = col[i];
    int b = t >> 7;
    int pos = gl[b] + atomicAdd(&lcur[b], 1);
    pairs[pos] = s | ((t & (TILE - 1)) << 20);
  }
}

// ---------------- per-tile CSR: node-ordered srcs, starts[], dinv ---------------
__global__ __launch_bounds__(256) void k_csr(const int* __restrict__ pairs,
                                             const int* __restrict__ base,
                                             int* __restrict__ starts,
                                             int* __restrict__ srcs,
                                             float* __restrict__ dinv,
                                             int n, int e) {
  __shared__ int cnt[TILE];
  __shared__ int cur[TILE];
  __shared__ int sc[TILE];
  int tid = threadIdx.x;
  int b = blockIdx.x;
  int tile0 = b * TILE;
  if (tid < TILE) cnt[tid] = 0;
  __syncthreads();
  int e0 = base[b], e1 = base[b + 1];
  for (int i = e0 + tid; i < e1; i += 256)
    atomicAdd(&cnt[(unsigned)pairs[i] >> 20], 1);
  __syncthreads();
  int c = (tid < TILE) ? cnt[tid] : 0;
  if (tid < TILE) sc[tid] = c;
  __syncthreads();
  for (int off = 1; off < TILE; off <<= 1) {
    int t = (tid < TILE && tid >= off) ? sc[tid - off] : 0;
    __syncthreads();
    if (tid < TILE) sc[tid] += t;
    __syncthreads();
  }
  if (tid < TILE) {
    int excl = sc[tid] - c;
    cur[tid] = excl;
    int node = tile0 + tid;
    if (node < n) {
      starts[node] = e0 + excl;
      dinv[node] = rsqrtf(1.0f + (float)c);
    }
  }
  if (b == 0 && tid == 0) starts[n] = e;
  __syncthreads();
  for (int i = e0 + tid; i < e1; i += 256) {
    int p = pairs[i];
    int pos = atomicAdd(&cur[(unsigned)p >> 20], 1);
    srcs[e0 + pos] = p & 0xFFFFF;
  }
}

// ---------------- xs (fp16) = dinv[node] * x  (premultiplied rows) --------------
__global__ __launch_bounds__(256) void k_xs(const float* __restrict__ x,
                                            const float* __restrict__ dinv,
                                            __half2* __restrict__ xh, int n32) {
  int i = blockIdx.x * 256 + threadIdx.x;
  if (i < n32) {
    float2 v = ((const float2*)x)[i];
    float d = dinv[i >> 5];
    xh[i] = __floats2half2_rn(v.x * d, v.y * d);
  }
}

// ---------------- WW = W1@W2 (64x64), bw = b1^T @ W2 ----------------------------
__global__ __launch_bounds__(256) void k_w12(const float* __restrict__ W1,
                                             const float* __restrict__ W2,
                                             const float* __restrict__ b1,
                                             float* __restrict__ WW,
                                             float* __restrict__ bw) {
  __shared__ float w1[4096], w2[4096];
  int tid = threadIdx.x;
  for (int i = tid; i < 4096; i += 256) { w1[i] = W1[i]; w2[i] = W2[i]; }
  __syncthreads();
  for (int p = tid; p < 4096; p += 256) {
    int k = p >> 6, d = p & 63;
    float a = 0.f;
    for (int m = 0; m < 64; ++m) a += w1[k * 64 + m] * w2[m * 64 + d];
    WW[p] = a;
  }
  if (tid < 64) {
    float a = 0.f;
    for (int k = 0; k < 64; ++k) a += b1[k] * w2[k * 64 + tid];
    bw[tid] = a;
  }
}

// --------- accumulate 8 halves of a float4-of-half2 into 4 float2 accs ---------
__device__ __forceinline__ void acc8(float2& a0, float2& a1, float2& a2,
                                     float2& a3, float4 v) {
  const __half2* hp = (const __half2*)&v;
  float2 t;
  t = __half22float2(hp[0]); a0.x += t.x; a0.y += t.y;
  t = __half22float2(hp[1]); a1.x += t.x; a1.y += t.y;
  t = __half22float2(hp[2]); a2.x += t.x; a2.y += t.y;
  t = __half22float2(hp[3]); a3.x += t.x; a3.y += t.y;
}

// ------- gather1: z1s = dc^2 * (xs_self + sum xs[srcs]); fused u = A_hat*1 ------
// 8 nodes per wave; 8 lanes per node, each lane one float4 (16 B) of the row.
__global__ __launch_bounds__(256) void k_gather1(const int* __restrict__ starts,
                                                 const int* __restrict__ srcs,
                                                 const float* __restrict__ dinv,
                                                 const __half2* __restrict__ xh,
                                                 __half2* __restrict__ z1h,
                                                 float* __restrict__ u, int n) {
  int node = blockIdx.x * 32 + (threadIdx.x >> 3);
  if (node >= n) return;
  int l = threadIdx.x & 7;
  int s = starts[node];
  int deg = starts[node + 1] - s;
  float dc = dinv[node];
  const float4* xf = (const float4*)xh;
  float4 sv = xf[(size_t)node * 8 + l];
  float2 a0 = make_float2(0.f, 0.f), a1 = a0, a2 = a0, a3 = a0;
  acc8(a0, a1, a2, a3, sv);  // self term (xs_self)
  float wsum = 0.f;
  int j = 0;
  for (; j + 3 < deg; j += 4) {
    int r0 = srcs[s + j + 0];
    int r1 = srcs[s + j + 1];
    int r2 = srcs[s + j + 2];
    int r3 = srcs[s + j + 3];
    float4 v0 = xf[(size_t)r0 * 8 + l];
    float4 v1 = xf[(size_t)r1 * 8 + l];
    float4 v2 = xf[(size_t)r2 * 8 + l];
    float4 v3 = xf[(size_t)r3 * 8 + l];
    wsum += dinv[r0] + dinv[r1] + dinv[r2] + dinv[r3];
    acc8(a0, a1, a2, a3, v0);
    acc8(a0, a1, a2, a3, v1);
    acc8(a0, a1, a2, a3, v2);
    acc8(a0, a1, a2, a3, v3);
  }
  for (; j < deg; ++j) {
    int r = srcs[s + j];
    float4 v = xf[(size_t)r * 8 + l];
    wsum += dinv[r];
    acc8(a0, a1, a2, a3, v);
  }
  float s2 = dc * dc;
  float4 ov;
  __half2* op = (__half2*)&ov;
  op[0] = __floats2half2_rn(s2 * a0.x, s2 * a0.y);
  op[1] = __floats2half2_rn(s2 * a1.x, s2 * a1.y);
  op[2] = __floats2half2_rn(s2 * a2.x, s2 * a2.y);
  op[3] = __floats2half2_rn(s2 * a3.x, s2 * a3.y);
  ((float4*)z1h)[(size_t)node * 8 + l] = ov;
  if (l == 0) u[node] = dc * (dc + wsum);
}

// ------- gather2: z2 (fp32) = dc * (z1s_self + sum z1s[srcs]) -------------------
// no per-edge dinv needed: normalization is baked into z1s.
__global__ __launch_bounds__(256) void k_gather2(const int* __restrict__ starts,
                                                 const int* __restrict__ srcs,
                                                 const float* __restrict__ dinv,
                                                 const __half2* __restrict__ z1h,
                                                 float* __restrict__ z2, int n) {
  int node = blockIdx.x * 32 + (threadIdx.x >> 3);
  if (node >= n) return;
  int l = threadIdx.x & 7;
  int s = starts[node];
  int deg = starts[node + 1] - s;
  float dc = dinv[node];
  const float4* xf = (const float4*)z1h;
  float4 sv = xf[(size_t)node * 8 + l];
  float2 a0 = make_float2(0.f, 0.f), a1 = a0, a2 = a0, a3 = a0;
  acc8(a0, a1, a2, a3, sv);  // self term (z1s_self)
  int j = 0;
  for (; j + 3 < deg; j += 4) {
    int r0 = srcs[s + j + 0];
    int r1 = srcs[s + j + 1];
    int r2 = srcs[s + j + 2];
    int r3 = srcs[s + j + 3];
    float4 v0 = xf[(size_t)r0 * 8 + l];
    float4 v1 = xf[(size_t)r1 * 8 + l];
    float4 v2 = xf[(size_t)r2 * 8 + l];
    float4 v3 = xf[(size_t)r3 * 8 + l];
    acc8(a0, a1, a2, a3, v0);
    acc8(a0, a1, a2, a3, v1);
    acc8(a0, a1, a2, a3, v2);
    acc8(a0, a1, a2, a3, v3);
  }
  for (; j < deg; ++j) {
    int r = srcs[s + j];
    float4 v = xf[(size_t)r * 8 + l];
    acc8(a0, a1, a2, a3, v);
  }
  float4* zr = (float4*)(z2 + (size_t)node * 64);
  zr[l * 2 + 0] = make_float4(dc * a0.x, dc * a0.y, dc * a1.x, dc * a1.y);
  zr[l * 2 + 1] = make_float4(dc * a2.x, dc * a2.y, dc * a3.x, dc * a3.y);
}

// ---------------- pool z2 rows, u, and counts (batch sorted) --------------------
__global__ void k_pool2(const float* __restrict__ z2, const float* __restrict__ u,
                        const int* __restrict__ batch, float* __restrict__ S,
                        float* __restrict__ T, float* __restrict__ cntf, int n) {
  int d = threadIdx.x;
  int start = blockIdx.x * 64;
  if (start >= n) return;
  int end = min(start + 64, n);
  int curg = batch[start];
  float acc = 0.f, cnt = 0.f, ua = 0.f;
  for (int i = start; i < end; ++i) {
    int g = batch[i];
    if (g != curg) {
      unsafeAtomicAdd(&S[curg * 64 + d], acc);
      if (d == 0) {
        unsafeAtomicAdd(&cntf[curg], cnt);
        unsafeAtomicAdd(&T[curg], ua);
      }
      acc = 0.f; cnt = 0.f; ua = 0.f;
      curg = g;
    }
    acc += z2[(size_t)i * 64 + d];
    if (d == 0) { cnt += 1.f; ua += u[i]; }
  }
  unsafeAtomicAdd(&S[curg * 64 + d], acc);
  if (d == 0) {
    unsafeAtomicAdd(&cntf[curg], cnt);
    unsafeAtomicAdd(&T[curg], ua);
  }
}

// ---------------- final: out[g] = (S[g]@WW + T[g]*bw)/cnt + b2 ------------------
__global__ __launch_bounds__(256) void k_final2(const float* __restrict__ S,
                                                const float* __restrict__ T,
                                                const float* __restrict__ cntf,
                                                const float* __restrict__ WW,
                                                const float* __restrict__ bw,
                                                const float* __restrict__ b2,
                                                float* __restrict__ out) {
  __shared__ float sS[4096], sW[4096];
  int tid = threadIdx.x;
  for (int i = tid; i < 4096; i += 256) { sS[i] = S[i]; sW[i] = WW[i]; }
  __syncthreads();
  for (int p = tid; p < 4096; p += 256) {
    int g = p >> 6, d = p & 63;
    float a = 0.f;
    for (int k = 0; k < 64; ++k) a += sS[g * 64 + k] * sW[k * 64 + d];
    float c = fmaxf(cntf[g], 1.0f);
    out[p] = (a + T[g] * bw[d]) / c + b2[d];
  }
}

extern "C" void kernel_launch(void* const* d_in, const int* in_sizes, int n_in,
                              void* d_out, int out_size, void* d_ws, size_t ws_size,
                              hipStream_t stream) {
  const float* x = (const float*)d_in[0];
  const int* ei = (const int*)d_in[1];
  const int* bat = (const int*)d_in[2];
  const float* W1 = (const float*)d_in[3];
  const float* b1 = (const float*)d_in[4];
  const float* W2 = (const float*)d_in[5];
  const float* b2 = (const float*)d_in[6];
  float* out = (float*)d_out;

  int n = in_sizes[0] / 64;  // 100000
  int e = in_sizes[1] / 2;   // 1000000
  const int* rowp = ei;      // sources
  const int* colp = ei + e;  // targets
  int nb = (n + TILE - 1) / TILE;      // 782 buckets (< NBMAX)
  int chunk = (e + NBLK - 1) / NBLK;   // edges per binning block

  // workspace (4B alloc units): [S][cntf][T] zeroed | gcount, base, cnt_m,
  // dinv, starts, srcs, u, WW, bw, xh, z1h, z2 (pairs alias z2).  ~47 MB.
  char* ws = (char*)d_ws;
  size_t off = 0;
  auto alloc = [&](size_t elems) {
    void* p = ws + off;
    off += ((elems * 4 + 255) & ~(size_t)255);
    return p;
  };
  float* S = (float*)alloc(NG * DFEAT);
  float* cntf = (float*)alloc(NG);
  float* T = (float*)alloc(NG);
  size_t zbytes = off;
  int* gcount = (int*)alloc(nb);
  int* base = (int*)alloc(nb + 1);
  int* cnt_m = (int*)alloc((size_t)NBLK * nb);
  float* dinv = (float*)alloc(n);
  int* starts = (int*)alloc(n + 1);
  int* srcs = (int*)alloc(e);
  float* u = (float*)alloc(n);
  float* WW = (float*)alloc(DFEAT * DFEAT);
  float* bw = (float*)alloc(DFEAT);
  __half2* xh = (__half2*)alloc((size_t)n * 32);   // n*64 halves (premultiplied)
  __half2* z1h = (__half2*)alloc((size_t)n * 32);  // n*64 halves (z1s = dinv*z1)
  float* z2 = (float*)alloc((size_t)n * 64);
  int* pairs = (int*)z2;  // dead after k_csr; z2 first written by gather2

  int nbw = (n + 31) / 32;  // gathers: 8 nodes/wave, 32 per block
  int n32 = n * 32;         // half2 count

  hipMemsetAsync(S, 0, zbytes, stream);
  k_cnt<<<NBLK, 256, 0, stream>>>(colp, cnt_m, e, nb, chunk);
  k_colscan<<<nb, 256, 0, stream>>>(cnt_m, gcount, nb);
  k_bscan<<<1, 1024, 0, stream>>>(gcount, base, nb);
  k_bin2<<<NBLK, 256, 0, stream>>>(rowp, colp, base, cnt_m, pairs, e, nb, chunk);
  k_csr<<<nb, 256, 0, stream>>>(pairs, base, starts, srcs, dinv, n, e);
  k_xs<<<(n32 + 255) / 256, 256, 0, stream>>>(x, dinv, xh, n32);
  k_w12<<<1, 256, 0, stream>>>(W1, W2, b1, WW, bw);

  // layer 1: z1s = dinv^2*(xs_self + sum xs) (+ fused u)
  // layer 2: z2 = dinv*(z1s_self + sum z1s)
  k_gather1<<<nbw, 256, 0, stream>>>(starts, srcs, dinv, xh, z1h, u, n);
  k_gather2<<<nbw, 256, 0, stream>>>(starts, srcs, dinv, z1h, z2, n);

  // pool + tiny final matmul
  k_pool2<<<(n + 63) / 64, 64, 0, stream>>>(z2, u, bat, S, T, cntf, n);
  k_final2<<<1, 256, 0, stream>>>(S, T, cntf, WW, bw, b2, out);
}